// Round 1
// baseline (842.118 us; speedup 1.0000x reference)
//
#include <hip/hip_runtime.h>

#define F_IN 128
#define HID  64

// ---------------- degree / norm ----------------
__global__ void k_deg_init(float* __restrict__ deg, int N) {
    int i = blockIdx.x * blockDim.x + threadIdx.x;
    if (i < N) deg[i] = 1.0f;  // self-loop
}

__global__ void k_deg_edges(const int* __restrict__ dst, float* __restrict__ deg, int E) {
    int e = blockIdx.x * blockDim.x + threadIdx.x;
    if (e < E) atomicAdd(&deg[dst[e]], 1.0f);
}

__global__ void k_dinv(float* __restrict__ deg, int N) {
    int i = blockIdx.x * blockDim.x + threadIdx.x;
    if (i < N) deg[i] = rsqrtf(deg[i]);  // deg >= 1 always (self-loops)
}

// ---------------- layer 1 GEMM: h = x @ W1  [N,128]x[128,64] ----------------
__launch_bounds__(256)
__global__ void k_gemm1(const float* __restrict__ x, const float* __restrict__ W1,
                        float* __restrict__ h, int N) {
    __shared__ float sW[F_IN * HID];  // 32 KB
    for (int i = threadIdx.x * 4; i < F_IN * HID; i += 256 * 4)
        *(float4*)&sW[i] = *(const float4*)&W1[i];
    __syncthreads();

    int lane = threadIdx.x & 63;
    int wid  = (blockIdx.x * blockDim.x + threadIdx.x) >> 6;
    int nw   = (gridDim.x * blockDim.x) >> 6;
    for (int r = wid; r < N; r += nw) {
        const float* xr = x + (size_t)r * F_IN;
        float acc = 0.f;
#pragma unroll
        for (int k = 0; k < F_IN; ++k)
            acc = fmaf(xr[k], sW[k * HID + lane], acc);  // xr[k] wave-uniform (L1 broadcast)
        h[(size_t)r * HID + lane] = acc;
    }
}

// ---------------- layer 1 scatter: agg[dst] += h[src] * dinv[src]*dinv[dst] ----------------
__launch_bounds__(256)
__global__ void k_agg1(const int* __restrict__ src, const int* __restrict__ dst,
                       const float* __restrict__ dinv, const float* __restrict__ h,
                       float* __restrict__ agg, int E) {
    int lane = threadIdx.x & 63;
    int wid  = (blockIdx.x * blockDim.x + threadIdx.x) >> 6;
    int nw   = (gridDim.x * blockDim.x) >> 6;
    for (int e = wid; e < E; e += nw) {
        int s = src[e], d = dst[e];
        float norm = dinv[s] * dinv[d];
        float v = h[(size_t)s * HID + lane] * norm;
        atomicAdd(&agg[(size_t)d * HID + lane], v);
    }
}

// ---------------- self-loop + bias + ReLU + layer-2 projection: z = relu(h1) @ W2 ----------------
__launch_bounds__(256)
__global__ void k_relu_proj(const float* __restrict__ agg, const float* __restrict__ h,
                            const float* __restrict__ dinv, const float* __restrict__ b1,
                            const float* __restrict__ W2, float* __restrict__ z, int N) {
    int lane = threadIdx.x & 63;
    int wid  = (blockIdx.x * blockDim.x + threadIdx.x) >> 6;
    int nw   = (gridDim.x * blockDim.x) >> 6;
    for (int r = wid; r < N; r += nw) {
        float di = dinv[r];
        float v = agg[(size_t)r * HID + lane] + h[(size_t)r * HID + lane] * (di * di) + b1[lane];
        v = fmaxf(v, 0.f);
        float p = v * W2[lane];
#pragma unroll
        for (int off = 32; off > 0; off >>= 1)
            p += __shfl_down(p, off, 64);
        if (lane == 0) z[r] = p;
    }
}

// ---------------- layer 2 scatter (scalar): out[dst] += z[src] * norm ----------------
__global__ void k_agg2(const int* __restrict__ src, const int* __restrict__ dst,
                       const float* __restrict__ dinv, const float* __restrict__ z,
                       float* __restrict__ out, int E) {
    int e = blockIdx.x * blockDim.x + threadIdx.x;
    if (e < E) {
        int s = src[e], d = dst[e];
        atomicAdd(&out[d], z[s] * dinv[s] * dinv[d]);
    }
}

// ---------------- final: add self-loop + b2 ----------------
__global__ void k_final(float* __restrict__ out, const float* __restrict__ z,
                        const float* __restrict__ dinv, const float* __restrict__ b2, int N) {
    int i = blockIdx.x * blockDim.x + threadIdx.x;
    if (i < N) {
        float di = dinv[i];
        out[i] += z[i] * di * di + b2[0];
    }
}

extern "C" void kernel_launch(void* const* d_in, const int* in_sizes, int n_in,
                              void* d_out, int out_size, void* d_ws, size_t ws_size,
                              hipStream_t stream) {
    const float* x  = (const float*)d_in[0];
    const int*   ei = (const int*)d_in[1];   // [2, E] int32 (JAX canonicalizes int64->int32)
    const float* W1 = (const float*)d_in[2];
    const float* b1 = (const float*)d_in[3];
    const float* W2 = (const float*)d_in[4];
    const float* b2 = (const float*)d_in[5];
    float* out = (float*)d_out;

    const int N = in_sizes[0] / F_IN;     // 100000
    const int E = in_sizes[1] / 2;        // 1600000
    const int* src = ei;
    const int* dst = ei + E;

    // workspace layout
    char* ws = (char*)d_ws;
    size_t off = 0;
    float* deg = (float*)(ws + off); off += (((size_t)N * 4 + 255) & ~255ULL);   // deg -> dinv (in place)
    float* h   = (float*)(ws + off); off += (size_t)N * HID * 4;                 // h = x@W1
    float* agg = (float*)(ws + off); off += (size_t)N * HID * 4;                 // layer-1 aggregate
    float* z   = (float*)(ws + off); off += (((size_t)N * 4 + 255) & ~255ULL);   // z = relu(h1)@W2

    // zero-init accumulators (ws/d_out are poisoned before every launch)
    hipMemsetAsync(agg, 0, (size_t)N * HID * 4, stream);
    hipMemsetAsync(out, 0, (size_t)N * 4, stream);

    // degree + dinv
    k_deg_init<<<(N + 255) / 256, 256, 0, stream>>>(deg, N);
    k_deg_edges<<<(E + 255) / 256, 256, 0, stream>>>(dst, deg, E);
    k_dinv<<<(N + 255) / 256, 256, 0, stream>>>(deg, N);

    // h = x @ W1
    k_gemm1<<<2048, 256, 0, stream>>>(x, W1, h, N);

    // layer-1 edge scatter (wave per edge)
    k_agg1<<<16384, 256, 0, stream>>>(src, dst, deg, h, agg, E);

    // self-loop + bias + relu + project to scalar
    k_relu_proj<<<4096, 256, 0, stream>>>(agg, h, deg, b1, W2, z, N);

    // layer-2 edge scatter (thread per edge)
    k_agg2<<<(E + 255) / 256, 256, 0, stream>>>(src, dst, deg, z, out, E);

    // self-loop + bias
    k_final<<<(N + 255) / 256, 256, 0, stream>>>(out, z, deg, b2, N);
}

// Round 2
// 454.124 us; speedup vs baseline: 1.8544x; 1.8544x over previous
//
#include <hip/hip_runtime.h>

#define F_IN 128
#define HID  64

// ---------------- histogram of dst (edge-only degrees) ----------------
__global__ void k_hist(const int* __restrict__ dst, int* __restrict__ counts, int E) {
    int e = blockIdx.x * blockDim.x + threadIdx.x;
    if (e < E) atomicAdd(&counts[dst[e]], 1);
}

// ---------------- scan step 1: per-block (1024-elem chunk) sums ----------------
__global__ void k_scan_block_sums(const int* __restrict__ counts, int* __restrict__ partials, int N) {
    __shared__ int lds[4];
    int b = blockIdx.x, t = threadIdx.x;
    int base = b * 1024 + t * 4;
    int s = 0;
#pragma unroll
    for (int i = 0; i < 4; ++i) { int idx = base + i; if (idx < N) s += counts[idx]; }
#pragma unroll
    for (int off = 32; off; off >>= 1) s += __shfl_down(s, off, 64);
    if ((t & 63) == 0) lds[t >> 6] = s;
    __syncthreads();
    if (t == 0) partials[b] = lds[0] + lds[1] + lds[2] + lds[3];
}

// ---------------- scan step 2: exclusive scan of partials (1 block, 1024 thr) ----------------
__global__ void k_scan_partials(int* __restrict__ partials, int NB) {
    __shared__ int wtot[16];
    int t = threadIdx.x, lane = t & 63, w = t >> 6;
    int v = (t < NB) ? partials[t] : 0;
    int s = v;
#pragma unroll
    for (int d = 1; d < 64; d <<= 1) { int u = __shfl_up(s, d, 64); if (lane >= d) s += u; }
    if (lane == 63) wtot[w] = s;
    __syncthreads();
    int woff = 0;
    for (int i = 0; i < w; ++i) woff += wtot[i];
    if (t < NB) partials[t] = s - v + woff;   // exclusive
}

// ---------------- scan step 3: apply -> offs, cursor, dinv ----------------
__global__ void k_scan_apply(const int* __restrict__ counts, const int* __restrict__ partials,
                             int* __restrict__ offs, int* __restrict__ cursor,
                             float* __restrict__ dinv, int N) {
    __shared__ int wsum[4];
    int b = blockIdx.x, t = threadIdx.x, lane = t & 63, w = t >> 6;
    int base = b * 1024 + t * 4;
    int c[4]; int s = 0;
#pragma unroll
    for (int i = 0; i < 4; ++i) { int idx = base + i; c[i] = (idx < N) ? counts[idx] : 0; s += c[i]; }
    int v = s;
#pragma unroll
    for (int d = 1; d < 64; d <<= 1) { int u = __shfl_up(v, d, 64); if (lane >= d) v += u; }
    int excl = v - s;
    if (lane == 63) wsum[w] = v;
    __syncthreads();
    int woff = 0;
    for (int i = 0; i < w; ++i) woff += wsum[i];
    int run = partials[b] + woff + excl;
#pragma unroll
    for (int i = 0; i < 4; ++i) {
        int idx = base + i;
        if (idx < N) {
            offs[idx] = run; cursor[idx] = run; run += c[i];
            dinv[idx] = rsqrtf((float)(c[i] + 1));   // +1 self-loop
        }
    }
}

// ---------------- fill CSR: csr[pos] = {src, norm} ----------------
__global__ void k_fill(const int* __restrict__ src, const int* __restrict__ dst,
                       const float* __restrict__ dinv, int* __restrict__ cursor,
                       int2* __restrict__ csr, int E) {
    int e = blockIdx.x * blockDim.x + threadIdx.x;
    if (e < E) {
        int s = src[e], d = dst[e];
        int pos = atomicAdd(&cursor[d], 1);
        float nv = dinv[s] * dinv[d];
        csr[pos] = make_int2(s, __float_as_int(nv));
    }
}

// ---------------- layer 1 GEMM: h = x @ W1, 8 rows per wave ----------------
__launch_bounds__(256)
__global__ void k_gemm1(const float* __restrict__ x, const float* __restrict__ W1,
                        float* __restrict__ h, int N) {
    __shared__ float sW[F_IN * HID];  // 32 KB
    for (int i = threadIdx.x * 4; i < F_IN * HID; i += 1024)
        *(float4*)&sW[i] = *(const float4*)&W1[i];
    __syncthreads();

    int lane = threadIdx.x & 63;
    int wid  = blockIdx.x * 4 + (threadIdx.x >> 6);
    int r0   = wid * 8;
    if (r0 >= N) return;
    const float* xr = x + (size_t)r0 * F_IN;
    float acc[8] = {0.f, 0.f, 0.f, 0.f, 0.f, 0.f, 0.f, 0.f};

    if (r0 + 8 <= N) {
        for (int k = 0; k < F_IN; k += 4) {
            float4 xv[8];
#pragma unroll
            for (int i = 0; i < 8; ++i) xv[i] = *(const float4*)&xr[(size_t)i * F_IN + k];
#pragma unroll
            for (int kk = 0; kk < 4; ++kk) {
                float w = sW[(k + kk) * HID + lane];
#pragma unroll
                for (int i = 0; i < 8; ++i)
                    acc[i] = fmaf(((const float*)&xv[i])[kk], w, acc[i]);
            }
        }
#pragma unroll
        for (int i = 0; i < 8; ++i) h[((size_t)r0 + i) * HID + lane] = acc[i];
    } else {
        int nr = N - r0;
        for (int k = 0; k < F_IN; ++k) {
            float w = sW[k * HID + lane];
            for (int i = 0; i < nr; ++i)
                acc[i] = fmaf(xr[(size_t)i * F_IN + k], w, acc[i]);
        }
        for (int i = 0; i < nr; ++i) h[((size_t)r0 + i) * HID + lane] = acc[i];
    }
}

// ---------------- layer 1 gather + self-loop + bias + ReLU + @W2 ----------------
__launch_bounds__(256)
__global__ void k_gather1(const int2* __restrict__ csr, const int* __restrict__ offs,
                          const int* __restrict__ counts, const float* __restrict__ h,
                          const float* __restrict__ dinv, const float* __restrict__ b1,
                          const float* __restrict__ W2, float* __restrict__ z, int N) {
    int lane = threadIdx.x & 63;
    int r = blockIdx.x * 4 + (threadIdx.x >> 6);
    if (r >= N) return;
    int beg = offs[r], cnt = counts[r];
    float acc0 = 0.f, acc1 = 0.f;
    int j = 0;
    for (; j + 2 <= cnt; j += 2) {
        int2 e0 = csr[beg + j];
        int2 e1 = csr[beg + j + 1];
        acc0 = fmaf(h[(size_t)e0.x * HID + lane], __int_as_float(e0.y), acc0);
        acc1 = fmaf(h[(size_t)e1.x * HID + lane], __int_as_float(e1.y), acc1);
    }
    if (j < cnt) {
        int2 e0 = csr[beg + j];
        acc0 = fmaf(h[(size_t)e0.x * HID + lane], __int_as_float(e0.y), acc0);
    }
    float di = dinv[r];
    float v = acc0 + acc1 + h[(size_t)r * HID + lane] * (di * di) + b1[lane];
    v = fmaxf(v, 0.f);
    float p = v * W2[lane];
#pragma unroll
    for (int off = 32; off; off >>= 1) p += __shfl_down(p, off, 64);
    if (lane == 0) z[r] = p;
}

// ---------------- layer 2 gather (scalar) + self-loop + b2 ----------------
__global__ void k_gather2(const int2* __restrict__ csr, const int* __restrict__ offs,
                          const int* __restrict__ counts, const float* __restrict__ z,
                          const float* __restrict__ dinv, const float* __restrict__ b2,
                          float* __restrict__ out, int N) {
    int i = blockIdx.x * blockDim.x + threadIdx.x;
    if (i < N) {
        int beg = offs[i], cnt = counts[i];
        float acc = 0.f;
        for (int j = 0; j < cnt; ++j) {
            int2 e = csr[beg + j];
            acc = fmaf(z[e.x], __int_as_float(e.y), acc);
        }
        float di = dinv[i];
        out[i] = acc + z[i] * di * di + b2[0];
    }
}

extern "C" void kernel_launch(void* const* d_in, const int* in_sizes, int n_in,
                              void* d_out, int out_size, void* d_ws, size_t ws_size,
                              hipStream_t stream) {
    const float* x  = (const float*)d_in[0];
    const int*   ei = (const int*)d_in[1];   // [2, E] int32
    const float* W1 = (const float*)d_in[2];
    const float* b1 = (const float*)d_in[3];
    const float* W2 = (const float*)d_in[4];
    const float* b2 = (const float*)d_in[5];
    float* out = (float*)d_out;

    const int N = in_sizes[0] / F_IN;     // 100000
    const int E = in_sizes[1] / 2;        // 1600000
    const int* src = ei;
    const int* dst = ei + E;

    // workspace layout (all 256B-aligned)
    char* ws = (char*)d_ws;
    size_t off = 0;
    auto alloc = [&](size_t bytes) { void* p = ws + off; off += (bytes + 255) & ~255ULL; return p; };
    int*   counts   = (int*)  alloc((size_t)N * 4);
    int*   offs     = (int*)  alloc((size_t)N * 4);
    int*   cursor   = (int*)  alloc((size_t)N * 4);
    float* dinv     = (float*)alloc((size_t)N * 4);
    float* z        = (float*)alloc((size_t)N * 4);
    int*   partials = (int*)  alloc(1024 * 4);
    float* h        = (float*)alloc((size_t)N * HID * 4);
    int2*  csr      = (int2*) alloc((size_t)E * 8);

    const int NB = (N + 1023) / 1024;  // scan chunks

    hipMemsetAsync(counts, 0, (size_t)N * 4, stream);

    k_hist<<<(E + 255) / 256, 256, 0, stream>>>(dst, counts, E);
    k_scan_block_sums<<<NB, 256, 0, stream>>>(counts, partials, N);
    k_scan_partials<<<1, 1024, 0, stream>>>(partials, NB);
    k_scan_apply<<<NB, 256, 0, stream>>>(counts, partials, offs, cursor, dinv, N);
    k_fill<<<(E + 255) / 256, 256, 0, stream>>>(src, dst, dinv, cursor, csr, E);

    k_gemm1<<<(N + 31) / 32, 256, 0, stream>>>(x, W1, h, N);

    k_gather1<<<(N + 3) / 4, 256, 0, stream>>>(csr, offs, counts, h, dinv, b1, W2, z, N);
    k_gather2<<<(N + 255) / 256, 256, 0, stream>>>(csr, offs, counts, z, dinv, b2, out, N);
}

// Round 3
// 370.816 us; speedup vs baseline: 2.2710x; 1.2247x over previous
//
#include <hip/hip_runtime.h>

#define F_IN 128
#define HID  64

// ---------------- histogram of dst (edge-only degrees) ----------------
__global__ void k_hist(const int* __restrict__ dst, int* __restrict__ counts, int E) {
    int e = blockIdx.x * blockDim.x + threadIdx.x;
    if (e < E) atomicAdd(&counts[dst[e]], 1);
}

// ---------------- scan step 1: per-block (1024-elem chunk) sums ----------------
__global__ void k_scan_block_sums(const int* __restrict__ counts, int* __restrict__ partials, int N) {
    __shared__ int lds[4];
    int b = blockIdx.x, t = threadIdx.x;
    int base = b * 1024 + t * 4;
    int s = 0;
#pragma unroll
    for (int i = 0; i < 4; ++i) { int idx = base + i; if (idx < N) s += counts[idx]; }
#pragma unroll
    for (int off = 32; off; off >>= 1) s += __shfl_down(s, off, 64);
    if ((t & 63) == 0) lds[t >> 6] = s;
    __syncthreads();
    if (t == 0) partials[b] = lds[0] + lds[1] + lds[2] + lds[3];
}

// ---------------- scan step 2: exclusive scan of partials (1 block, 1024 thr) ----------------
__global__ void k_scan_partials(int* __restrict__ partials, int NB) {
    __shared__ int wtot[16];
    int t = threadIdx.x, lane = t & 63, w = t >> 6;
    int v = (t < NB) ? partials[t] : 0;
    int s = v;
#pragma unroll
    for (int d = 1; d < 64; d <<= 1) { int u = __shfl_up(s, d, 64); if (lane >= d) s += u; }
    if (lane == 63) wtot[w] = s;
    __syncthreads();
    int woff = 0;
    for (int i = 0; i < w; ++i) woff += wtot[i];
    if (t < NB) partials[t] = s - v + woff;   // exclusive
}

// ---------------- scan step 3: apply -> offs, cursor, dinv ----------------
__global__ void k_scan_apply(const int* __restrict__ counts, const int* __restrict__ partials,
                             int* __restrict__ offs, int* __restrict__ cursor,
                             float* __restrict__ dinv, int N) {
    __shared__ int wsum[4];
    int b = blockIdx.x, t = threadIdx.x, lane = t & 63, w = t >> 6;
    int base = b * 1024 + t * 4;
    int c[4]; int s = 0;
#pragma unroll
    for (int i = 0; i < 4; ++i) { int idx = base + i; c[i] = (idx < N) ? counts[idx] : 0; s += c[i]; }
    int v = s;
#pragma unroll
    for (int d = 1; d < 64; d <<= 1) { int u = __shfl_up(v, d, 64); if (lane >= d) v += u; }
    int excl = v - s;
    if (lane == 63) wsum[w] = v;
    __syncthreads();
    int woff = 0;
    for (int i = 0; i < w; ++i) woff += wsum[i];
    int run = partials[b] + woff + excl;
#pragma unroll
    for (int i = 0; i < 4; ++i) {
        int idx = base + i;
        if (idx < N) {
            offs[idx] = run; cursor[idx] = run; run += c[i];
            dinv[idx] = rsqrtf((float)(c[i] + 1));   // +1 self-loop
        }
    }
}

// ---------------- fill CSR: csr[pos] = {src, norm} ----------------
__global__ void k_fill(const int* __restrict__ src, const int* __restrict__ dst,
                       const float* __restrict__ dinv, int* __restrict__ cursor,
                       int2* __restrict__ csr, int E) {
    int e = blockIdx.x * blockDim.x + threadIdx.x;
    if (e < E) {
        int s = src[e], d = dst[e];
        int pos = atomicAdd(&cursor[d], 1);
        float nv = dinv[s] * dinv[d];
        csr[pos] = make_int2(s, __float_as_int(nv));
    }
}

// ---------------- layer 1 GEMM: h = x @ W1, one thread per row ----------------
// acc[64] in VGPRs; W1[k][c] has wave-uniform address -> scalar loads (K$),
// x row is per-lane private, read as 64B chunks. 64 independent FMA chains.
__launch_bounds__(256)
__global__ void k_gemm1(const float* __restrict__ x, const float* __restrict__ W1,
                        float* __restrict__ h, int N) {
    int tid = blockIdx.x * 256 + threadIdx.x;
    if (tid >= N) return;
    const float* xr = x + (size_t)tid * F_IN;
    float acc[HID];
#pragma unroll
    for (int c = 0; c < HID; ++c) acc[c] = 0.f;

    for (int k0 = 0; k0 < F_IN; k0 += 16) {
        float4 xv[4];
#pragma unroll
        for (int i = 0; i < 4; ++i) xv[i] = *(const float4*)&xr[k0 + 4 * i];
#pragma unroll
        for (int kk = 0; kk < 16; ++kk) {
            float xs = ((const float*)xv)[kk];
            const float* wrow = W1 + (k0 + kk) * HID;   // uniform -> s_load
#pragma unroll
            for (int c = 0; c < HID; ++c)
                acc[c] = fmaf(xs, wrow[c], acc[c]);
        }
    }
    float* hr = h + (size_t)tid * HID;
#pragma unroll
    for (int c = 0; c < HID; c += 4)
        *(float4*)&hr[c] = make_float4(acc[c], acc[c + 1], acc[c + 2], acc[c + 3]);
}

// ---------------- layer 1 gather + self-loop + bias + ReLU + @W2 ----------------
// wave per node; 4 groups of 16 lanes, group g takes edges j = g (mod 4);
// lane covers 4 cols (float4, 16B/lane). Cross-group reduce via shfl_xor.
__launch_bounds__(256)
__global__ void k_gather1(const int2* __restrict__ csr, const int* __restrict__ offs,
                          const int* __restrict__ counts, const float* __restrict__ h,
                          const float* __restrict__ dinv, const float* __restrict__ b1,
                          const float* __restrict__ W2, float* __restrict__ z, int N) {
    int lane = threadIdx.x & 63;
    int r = blockIdx.x * 4 + (threadIdx.x >> 6);
    if (r >= N) return;
    int g  = lane >> 4;       // edge phase 0..3
    int li = lane & 15;       // col group: cols 4*li .. 4*li+3
    int beg = offs[r], cnt = counts[r];

    float4 a0 = make_float4(0.f, 0.f, 0.f, 0.f);
    float4 a1 = make_float4(0.f, 0.f, 0.f, 0.f);
    int j = g;
    for (; j + 4 < cnt; j += 8) {
        int2 e0 = csr[beg + j];
        int2 e1 = csr[beg + j + 4];
        float n0 = __int_as_float(e0.y), n1 = __int_as_float(e1.y);
        float4 h0 = *(const float4*)&h[(size_t)e0.x * HID + li * 4];
        float4 h1 = *(const float4*)&h[(size_t)e1.x * HID + li * 4];
        a0.x = fmaf(h0.x, n0, a0.x); a0.y = fmaf(h0.y, n0, a0.y);
        a0.z = fmaf(h0.z, n0, a0.z); a0.w = fmaf(h0.w, n0, a0.w);
        a1.x = fmaf(h1.x, n1, a1.x); a1.y = fmaf(h1.y, n1, a1.y);
        a1.z = fmaf(h1.z, n1, a1.z); a1.w = fmaf(h1.w, n1, a1.w);
    }
    if (j < cnt) {
        int2 e0 = csr[beg + j];
        float n0 = __int_as_float(e0.y);
        float4 h0 = *(const float4*)&h[(size_t)e0.x * HID + li * 4];
        a0.x = fmaf(h0.x, n0, a0.x); a0.y = fmaf(h0.y, n0, a0.y);
        a0.z = fmaf(h0.z, n0, a0.z); a0.w = fmaf(h0.w, n0, a0.w);
    }
    a0.x += a1.x; a0.y += a1.y; a0.z += a1.z; a0.w += a1.w;

    // reduce across the 4 groups (lane bits 4,5)
    a0.x += __shfl_xor(a0.x, 16, 64); a0.y += __shfl_xor(a0.y, 16, 64);
    a0.z += __shfl_xor(a0.z, 16, 64); a0.w += __shfl_xor(a0.w, 16, 64);
    a0.x += __shfl_xor(a0.x, 32, 64); a0.y += __shfl_xor(a0.y, 32, 64);
    a0.z += __shfl_xor(a0.z, 32, 64); a0.w += __shfl_xor(a0.w, 32, 64);

    // self-loop + bias + relu + project
    float di = dinv[r]; float di2 = di * di;
    float4 hr = *(const float4*)&h[(size_t)r * HID + li * 4];
    float4 bv = *(const float4*)&b1[li * 4];
    float4 wv = *(const float4*)&W2[li * 4];
    float vx = fmaxf(a0.x + hr.x * di2 + bv.x, 0.f);
    float vy = fmaxf(a0.y + hr.y * di2 + bv.y, 0.f);
    float vz = fmaxf(a0.z + hr.z * di2 + bv.z, 0.f);
    float vw = fmaxf(a0.w + hr.w * di2 + bv.w, 0.f);
    float p = vx * wv.x + vy * wv.y + vz * wv.z + vw * wv.w;
    p += __shfl_xor(p, 1, 64);
    p += __shfl_xor(p, 2, 64);
    p += __shfl_xor(p, 4, 64);
    p += __shfl_xor(p, 8, 64);
    if (lane == 0) z[r] = p;
}

// ---------------- layer 2 gather: 16 lanes per node ----------------
__global__ void k_gather2(const int2* __restrict__ csr, const int* __restrict__ offs,
                          const int* __restrict__ counts, const float* __restrict__ z,
                          const float* __restrict__ dinv, const float* __restrict__ b2,
                          float* __restrict__ out, int N) {
    int t = blockIdx.x * blockDim.x + threadIdx.x;
    int r = t >> 4, li = t & 15;
    if (r >= N) return;
    int beg = offs[r], cnt = counts[r];
    float acc = 0.f;
    for (int j = li; j < cnt; j += 16) {
        int2 e = csr[beg + j];
        acc = fmaf(z[e.x], __int_as_float(e.y), acc);
    }
    acc += __shfl_xor(acc, 1, 64);
    acc += __shfl_xor(acc, 2, 64);
    acc += __shfl_xor(acc, 4, 64);
    acc += __shfl_xor(acc, 8, 64);
    if (li == 0) {
        float di = dinv[r];
        out[r] = acc + z[r] * di * di + b2[0];
    }
}

extern "C" void kernel_launch(void* const* d_in, const int* in_sizes, int n_in,
                              void* d_out, int out_size, void* d_ws, size_t ws_size,
                              hipStream_t stream) {
    const float* x  = (const float*)d_in[0];
    const int*   ei = (const int*)d_in[1];   // [2, E] int32
    const float* W1 = (const float*)d_in[2];
    const float* b1 = (const float*)d_in[3];
    const float* W2 = (const float*)d_in[4];
    const float* b2 = (const float*)d_in[5];
    float* out = (float*)d_out;

    const int N = in_sizes[0] / F_IN;     // 100000
    const int E = in_sizes[1] / 2;        // 1600000
    const int* src = ei;
    const int* dst = ei + E;

    // workspace layout (all 256B-aligned)
    char* ws = (char*)d_ws;
    size_t off = 0;
    auto alloc = [&](size_t bytes) { void* p = ws + off; off += (bytes + 255) & ~255ULL; return p; };
    int*   counts   = (int*)  alloc((size_t)N * 4);
    int*   offs     = (int*)  alloc((size_t)N * 4);
    int*   cursor   = (int*)  alloc((size_t)N * 4);
    float* dinv     = (float*)alloc((size_t)N * 4);
    float* z        = (float*)alloc((size_t)N * 4);
    int*   partials = (int*)  alloc(1024 * 4);
    float* h        = (float*)alloc((size_t)N * HID * 4);
    int2*  csr      = (int2*) alloc((size_t)E * 8);

    const int NB = (N + 1023) / 1024;  // scan chunks

    hipMemsetAsync(counts, 0, (size_t)N * 4, stream);

    k_hist<<<(E + 255) / 256, 256, 0, stream>>>(dst, counts, E);
    k_scan_block_sums<<<NB, 256, 0, stream>>>(counts, partials, N);
    k_scan_partials<<<1, 1024, 0, stream>>>(partials, NB);
    k_scan_apply<<<NB, 256, 0, stream>>>(counts, partials, offs, cursor, dinv, N);
    k_fill<<<(E + 255) / 256, 256, 0, stream>>>(src, dst, dinv, cursor, csr, E);

    k_gemm1<<<(N + 255) / 256, 256, 0, stream>>>(x, W1, h, N);

    k_gather1<<<(N + 3) / 4, 256, 0, stream>>>(csr, offs, counts, h, dinv, b1, W2, z, N);
    k_gather2<<<((size_t)N * 16 + 255) / 256, 256, 0, stream>>>(csr, offs, counts, z, dinv, b2, out, N);
}